// Round 16
// baseline (69.952 us; speedup 1.0000x reference)
//
#include <hip/hip_runtime.h>
#include <float.h>

// RoIPool (torch semantics: round(coords*scale), clamp, AdaptiveMaxPool2d bins)
// features: [B=4, C=128, H=64, W=64] fp32; rois: [N,5]; out: [N,128,7,7] fp32
//
// R16 change: L3-warming prepass. The harness's 256MiB 0xAA ws-poison evicts
// the 8MB feature tensor from L2+L3 before EVERY replay; the pool kernel then
// pays ~900cy cold-HBM latency on scattered 16B gathers. The prepass sweeps
// features linearly (float4, coalesced, ~1.3us at BW, perfect DRAM row
// locality) so the pool kernel gathers from warm L3 (~250cy) instead.
// Pool kernel = R15 best: global_load_lds DMA staging, SLAB=8 (8 blk/CU),
// dynamic tap loops + channel-pair, bank-rotating stride, needed-seg trim.
//
// Adaptive bin size <= h/P+2 <= 4 for h<=17 (R4/R6 bug: assumed 3).
// Wave-uniform-LDS-base rule (m104): interior lanes stay ACTIVE with clamped
// duplicate addresses; only loop-tail is exec-masked (suffix -> lane0 active).

#define POOL_P 7
#define NBINS  49
#define SPATIAL_SCALE 0.0625f
#define SLAB   8                    // channels per block (C/SLAB = 16 slabs)
#define MAXH   17                   // max crop rows in LDS tile
#define MAXW   20                   // col span: min(x1&~3, 44) .. +19 covers x1..x2
#define SEGS   (MAXW / 4)           // 5 float4 segments per (row,ch)
#define ROWF4  (SLAB * SEGS + 1)    // 41 f4 per row (pad -> 164 fl = 4 mod 32)
#define ROWFL  (ROWF4 * 4)          // 164 floats per row
#define HCH    (SLAB / 2)           // 4: channel-pair stride

// Linear sweep: pulls the whole feature tensor through L3 at full BW.
__global__ __launch_bounds__(256) void warm_kernel(
    const float4* __restrict__ feat4, float* __restrict__ ws, int nf4)
{
    const int i = blockIdx.x * 256 + threadIdx.x;
    if (i < nf4) {
        const float4 v = feat4[i];
        const float s = v.x + v.y + v.z + v.w;
        if (s != s)                      // never taken (data is finite);
            ws[blockIdx.x] = s;          // unprovable by compiler -> load kept
    }
}

__global__ __launch_bounds__(256) void roipool_kernel(
    const float* __restrict__ feat,
    const float* __restrict__ rois,
    float* __restrict__ out,
    int C, int H, int W, int N)
{
    __shared__ float4 lds4[MAXH * ROWF4];       // 697 f4 = 11152 B -> 8 blk/CU
    const float* lds = (const float*)lds4;

    const int bid  = blockIdx.x;
    const int slab = bid & 15;                  // 16 slabs of 8 channels
    const int n    = bid >> 4;
    const int tid  = threadIdx.x;

    // ROI decode (block-uniform)
    const float* r = rois + (size_t)n * 5;
    const int b  = (int)r[0];                                  // astype(int32) = trunc
    int x1 = max(__float2int_rn(r[1] * SPATIAL_SCALE), 0);     // jnp.round = half-to-even
    int y1 = max(__float2int_rn(r[2] * SPATIAL_SCALE), 0);
    int x2 = min(__float2int_rn(r[3] * SPATIAL_SCALE), W - 1);
    int y2 = min(__float2int_rn(r[4] * SPATIAL_SCALE), H - 1);

    const int h = y2 - y1 + 1;                  // 1..17 for this generator
    const int w = x2 - x1 + 1;
    const int xa = min(x1 & ~3, W - MAXW);      // aligned; xa+19 <= W-1; x2-xa <= 19

    const size_t HWs = (size_t)H * W;
    const float* fb  = feat + ((size_t)b * C + slab * SLAB) * HWs;

    const bool fast = (h <= MAXH) && (w <= MAXW - 3);

    if (fast) {
        const int sa = (x1 - xa) >> 2;          // first needed segment
        const int se = (x2 - xa) >> 2;          // last needed segment (incl)
        const int hf4 = h * ROWF4;              // <= 697; avg ~435
        for (int s = tid; s < hf4; s += 256) {
            const int row  = s / ROWF4;         // const divisors only
            const int rowc = min(row, h - 1);   // masked-tail lanes: valid addr
            int rem = s - row * ROWF4;
            if (rem >= SLAB * SEGS) rem = SLAB * SEGS - 1;   // pad slot -> dup
            int ch  = rem / SEGS;
            int seg = rem - ch * SEGS;
            seg = min(max(seg, sa), se);        // trimmed segs -> dup (never read)
            const float* g = fb + (size_t)ch * HWs
                                + (size_t)(y1 + rowc) * W + xa + seg * 4;
            __builtin_amdgcn_global_load_lds(
                (const __attribute__((address_space(1))) void*)g,
                (__attribute__((address_space(3))) void*)&lds4[s],
                16, 0, 0);
        }
    }
    __syncthreads();   // drains vmcnt -> all LDS writes landed

    // pool: one iteration = one bin x channel-pair (ch0, ch0+4); 196 iters
    for (int o = tid; o < NBINS * HCH; o += 256) {
        const int ch0 = o / NBINS;              // 0..3
        const int bin = o - ch0 * NBINS;
        const int px  = bin % POOL_P;
        const int py  = bin / POOL_P;

        // AdaptiveMaxPool2d: start=floor(i*h/P), end=ceil((i+1)*h/P)
        // non-negative operands -> C division == floor; ceil via (a+P-1)/P
        const int ys = y1 + (py * h) / POOL_P;
        const int ye = y1 + ((py + 1) * h + POOL_P - 1) / POOL_P;
        const int xs = x1 + (px * w) / POOL_P;
        const int xe = x1 + ((px + 1) * w + POOL_P - 1) / POOL_P;

        float m0 = -FLT_MAX, m1 = -FLT_MAX;     // empty bin -> finfo(f32).min
        if (fast) {
            // lds float index: (y-y1)*164 + ch*20 + (x-xa)
            const int base = ch0 * MAXW - y1 * ROWFL - xa;
            for (int y = ys; y < ye; ++y) {
                const int rowb = base + y * ROWFL;
                for (int x = xs; x < xe; ++x) {
                    m0 = fmaxf(m0, lds[rowb + x]);
                    m1 = fmaxf(m1, lds[rowb + HCH * MAXW + x]);   // +80 fl
                }
            }
        } else {
            // crop too big for LDS tile -> direct global pooling
            const float* f0 = fb + (size_t)ch0 * HWs;
            const float* f1 = f0 + (size_t)HCH * HWs;
            for (int y = ys; y < ye; ++y)
                for (int x = xs; x < xe; ++x) {
                    m0 = fmaxf(m0, f0[(size_t)y * W + x]);
                    m1 = fmaxf(m1, f1[(size_t)y * W + x]);
                }
        }
        const size_t ob = ((size_t)n * C + slab * SLAB + ch0) * NBINS + bin;
        out[ob] = m0;
        out[ob + (size_t)HCH * NBINS] = m1;
    }
}

extern "C" void kernel_launch(void* const* d_in, const int* in_sizes, int n_in,
                              void* d_out, int out_size, void* d_ws, size_t ws_size,
                              hipStream_t stream) {
    const float* features = (const float*)d_in[0];   // [B, C, H, W]
    const float* rois     = (const float*)d_in[1];   // [N, 5]
    float* out            = (float*)d_out;           // [N, C, 7, 7]

    const int C = 128, H = 64, W = 64;
    const int N = in_sizes[1] / 5;                   // 256
    const int nf4 = in_sizes[0] / 4;                 // 524288 float4

    // 1) warm L3 with a dense sweep (stream-ordered before the pool kernel)
    warm_kernel<<<(nf4 + 255) / 256, 256, 0, stream>>>(
        (const float4*)features, (float*)d_ws, nf4);

    // 2) pool from warm cache
    const int grid = N * (C / SLAB);                 // 4096
    roipool_kernel<<<grid, 256, 0, stream>>>(features, rois, out, C, H, W, N);
}

// Round 17
// 64.678 us; speedup vs baseline: 1.0815x; 1.0815x over previous
//
#include <hip/hip_runtime.h>
#include <float.h>

// RoIPool (torch semantics: round(coords*scale), clamp, AdaptiveMaxPool2d bins)
// features: [B=4, C=128, H=64, W=64] fp32; rois: [N,5]; out: [N,128,7,7] fp32
//
// FINAL = R15 best config (64.3us measured; R16 warm-prepass hurt +5.7 -> reverted).
// Block = (ROI, 8-channel slab), 4096 blocks: global_load_lds DMA staging,
// dynamic tap loops + channel-pair pool, bank-rotating LDS stride, needed-seg
// trim. Measured-null levers intentionally absent: XCD swizzle, NT stores,
// bank-pad beyond stride choice, warm prepass.
//
// Adaptive bin size <= h/P+2 <= 4 for h<=17 (R4/R6 bug: assumed 3).
// Wave-uniform-LDS-base rule (m104): interior lanes stay ACTIVE with clamped
// duplicate addresses; only loop-tail is exec-masked (suffix -> lane0 active).

#define POOL_P 7
#define NBINS  49
#define SPATIAL_SCALE 0.0625f
#define SLAB   8                    // channels per block (C/SLAB = 16 slabs)
#define MAXH   17                   // max crop rows in LDS tile
#define MAXW   20                   // col span: min(x1&~3, 44) .. +19 covers x1..x2
#define SEGS   (MAXW / 4)           // 5 float4 segments per (row,ch)
#define ROWF4  (SLAB * SEGS + 1)    // 41 f4 per row (pad -> 164 fl = 4 mod 32)
#define ROWFL  (ROWF4 * 4)          // 164 floats per row
#define HCH    (SLAB / 2)           // 4: channel-pair stride

__global__ __launch_bounds__(256) void roipool_kernel(
    const float* __restrict__ feat,
    const float* __restrict__ rois,
    float* __restrict__ out,
    int C, int H, int W, int N)
{
    __shared__ float4 lds4[MAXH * ROWF4];       // 697 f4 = 11152 B -> 8 blk/CU
    const float* lds = (const float*)lds4;

    const int bid  = blockIdx.x;
    const int slab = bid & 15;                  // 16 slabs of 8 channels
    const int n    = bid >> 4;
    const int tid  = threadIdx.x;

    // ROI decode (block-uniform)
    const float* r = rois + (size_t)n * 5;
    const int b  = (int)r[0];                                  // astype(int32) = trunc
    int x1 = max(__float2int_rn(r[1] * SPATIAL_SCALE), 0);     // jnp.round = half-to-even
    int y1 = max(__float2int_rn(r[2] * SPATIAL_SCALE), 0);
    int x2 = min(__float2int_rn(r[3] * SPATIAL_SCALE), W - 1);
    int y2 = min(__float2int_rn(r[4] * SPATIAL_SCALE), H - 1);

    const int h = y2 - y1 + 1;                  // 1..17 for this generator
    const int w = x2 - x1 + 1;
    const int xa = min(x1 & ~3, W - MAXW);      // aligned; xa+19 <= W-1; x2-xa <= 19

    const size_t HWs = (size_t)H * W;
    const float* fb  = feat + ((size_t)b * C + slab * SLAB) * HWs;

    const bool fast = (h <= MAXH) && (w <= MAXW - 3);

    if (fast) {
        const int sa = (x1 - xa) >> 2;          // first needed segment
        const int se = (x2 - xa) >> 2;          // last needed segment (incl)
        const int hf4 = h * ROWF4;              // <= 697; avg ~435
        for (int s = tid; s < hf4; s += 256) {
            const int row  = s / ROWF4;         // const divisors only
            const int rowc = min(row, h - 1);   // masked-tail lanes: valid addr
            int rem = s - row * ROWF4;
            if (rem >= SLAB * SEGS) rem = SLAB * SEGS - 1;   // pad slot -> dup
            int ch  = rem / SEGS;
            int seg = rem - ch * SEGS;
            seg = min(max(seg, sa), se);        // trimmed segs -> dup (never read)
            const float* g = fb + (size_t)ch * HWs
                                + (size_t)(y1 + rowc) * W + xa + seg * 4;
            __builtin_amdgcn_global_load_lds(
                (const __attribute__((address_space(1))) void*)g,
                (__attribute__((address_space(3))) void*)&lds4[s],
                16, 0, 0);
        }
    }
    __syncthreads();   // drains vmcnt -> all LDS writes landed

    // pool: one iteration = one bin x channel-pair (ch0, ch0+4); 196 iters
    for (int o = tid; o < NBINS * HCH; o += 256) {
        const int ch0 = o / NBINS;              // 0..3
        const int bin = o - ch0 * NBINS;
        const int px  = bin % POOL_P;
        const int py  = bin / POOL_P;

        // AdaptiveMaxPool2d: start=floor(i*h/P), end=ceil((i+1)*h/P)
        // non-negative operands -> C division == floor; ceil via (a+P-1)/P
        const int ys = y1 + (py * h) / POOL_P;
        const int ye = y1 + ((py + 1) * h + POOL_P - 1) / POOL_P;
        const int xs = x1 + (px * w) / POOL_P;
        const int xe = x1 + ((px + 1) * w + POOL_P - 1) / POOL_P;

        float m0 = -FLT_MAX, m1 = -FLT_MAX;     // empty bin -> finfo(f32).min
        if (fast) {
            // lds float index: (y-y1)*164 + ch*20 + (x-xa)
            const int base = ch0 * MAXW - y1 * ROWFL - xa;
            for (int y = ys; y < ye; ++y) {
                const int rowb = base + y * ROWFL;
                for (int x = xs; x < xe; ++x) {
                    m0 = fmaxf(m0, lds[rowb + x]);
                    m1 = fmaxf(m1, lds[rowb + HCH * MAXW + x]);   // +80 fl
                }
            }
        } else {
            // crop too big for LDS tile -> direct global pooling
            const float* f0 = fb + (size_t)ch0 * HWs;
            const float* f1 = f0 + (size_t)HCH * HWs;
            for (int y = ys; y < ye; ++y)
                for (int x = xs; x < xe; ++x) {
                    m0 = fmaxf(m0, f0[(size_t)y * W + x]);
                    m1 = fmaxf(m1, f1[(size_t)y * W + x]);
                }
        }
        const size_t ob = ((size_t)n * C + slab * SLAB + ch0) * NBINS + bin;
        out[ob] = m0;
        out[ob + (size_t)HCH * NBINS] = m1;
    }
}

extern "C" void kernel_launch(void* const* d_in, const int* in_sizes, int n_in,
                              void* d_out, int out_size, void* d_ws, size_t ws_size,
                              hipStream_t stream) {
    const float* features = (const float*)d_in[0];   // [B, C, H, W]
    const float* rois     = (const float*)d_in[1];   // [N, 5]
    float* out            = (float*)d_out;           // [N, C, 7, 7]

    const int C = 128, H = 64, W = 64;
    const int N = in_sizes[1] / 5;                   // 256

    const int grid = N * (C / SLAB);                 // 4096
    roipool_kernel<<<grid, 256, 0, stream>>>(features, rois, out, C, H, W, N);
}